// Round 9
// baseline (292.016 us; speedup 1.0000x reference)
//
#include <hip/hip_runtime.h>
#include <cstdint>
#include <cstddef>

// Static problem geometry
#define LEN_IN  21760
#define BATCH   2
#define MROWS   (BATCH * LEN_IN)   // 43520 = 64 * 680
// Levels: (128,128),(64,64),(32,32),(16,16); starts 0,16384,20480,21504

typedef _Float16 hv8 __attribute__((ext_vector_type(8)));
typedef float    fv4 __attribute__((ext_vector_type(4)));

#define AS1 __attribute__((address_space(1)))
#define AS3 __attribute__((address_space(3)))

// s_waitcnt imm (gfx9): vmcnt[3:0]=b3:0, expcnt=b6:4, lgkmcnt=b11:8, vmcnt[5:4]=b15:14
#define WAIT_VM(N)   __builtin_amdgcn_s_waitcnt(0x0F70 | (N))  // vmcnt(N), lgkm/exp nowait
#define WAIT_LGKM0() __builtin_amdgcn_s_waitcnt(0xC07F)        // lgkm(0) only
#define BAR()        __builtin_amdgcn_s_barrier()

__device__ __forceinline__ void gl_lds16(const _Float16* g, _Float16* l) {
  __builtin_amdgcn_global_load_lds((const AS1 void*)g, (AS3 void*)l, 16, 0, 0);
}

// ---------------------------------------------------------------------------
// Weight prep (as R8): transpose [K][N] -> [N][K] f16; Woff f16-split hi|lo.
// ---------------------------------------------------------------------------
__global__ __launch_bounds__(256) void cvt_weights(
    const float* __restrict__ Wv, const float* __restrict__ Woff,
    const float* __restrict__ Wa, const float* __restrict__ Wo,
    _Float16* __restrict__ WvT, _Float16* __restrict__ WoffT2,
    _Float16* __restrict__ WaT, _Float16* __restrict__ WoT)
{
  __shared__ float t[64][65];
  const int id = blockIdx.x, tid = threadIdx.x;
  const int c = tid & 63, r4 = tid >> 6;

  const float* src; _Float16* dst; int N; bool split = false; int nt, kt;
  if (id < 16)      { src = Wv;   dst = WvT;    N = 256; nt = id & 3;        kt = id >> 2; }
  else if (id < 32) { src = Woff; dst = WoffT2; N = 256; nt = (id - 16) & 3; kt = (id - 16) >> 2; split = true; }
  else if (id < 40) { src = Wa;   dst = WaT;    N = 128; nt = (id - 32) & 1; kt = (id - 32) >> 1; }
  else              { src = Wo;   dst = WoT;    N = 256; nt = (id - 40) & 3; kt = (id - 40) >> 2; }
  const int nb = nt * 64, kb = kt * 64;

#pragma unroll
  for (int rr = 0; rr < 16; ++rr) {
    const int r = rr * 4 + r4;
    t[r][c] = src[(size_t)(kb + r) * N + nb + c];
  }
  __syncthreads();
#pragma unroll
  for (int rr = 0; rr < 16; ++rr) {
    const int r = rr * 4 + r4;
    const float v = t[c][r];
    const _Float16 h = (_Float16)v;
    dst[(size_t)(nb + r) * 256 + kb + c] = h;
    if (split)
      dst[(size_t)(256 + nb + r) * 256 + kb + c] = (_Float16)(v - (float)h);
  }
}

// ---------------------------------------------------------------------------
// Activation cvt: query -> (qH, qL f16 split), flatten -> fH f16.
// 8 elems/thread; grid 10880 x 256 covers both tensors.
// ---------------------------------------------------------------------------
__global__ __launch_bounds__(256) void cvt_acts(
    const float* __restrict__ q, const float* __restrict__ f,
    _Float16* __restrict__ qH, _Float16* __restrict__ qL, _Float16* __restrict__ fH)
{
  const size_t NE8 = (size_t)MROWS * 32;   // NE/8
  const size_t id = (size_t)blockIdx.x * 256 + threadIdx.x;
  if (id < NE8) {
    const float4 f0 = *(const float4*)&q[id * 8];
    const float4 f1 = *(const float4*)&q[id * 8 + 4];
    const float fa[8] = {f0.x, f0.y, f0.z, f0.w, f1.x, f1.y, f1.z, f1.w};
    hv8 hh, ll;
#pragma unroll
    for (int e = 0; e < 8; ++e) {
      hh[e] = (_Float16)fa[e];
      ll[e] = (_Float16)(fa[e] - (float)hh[e]);
    }
    *(hv8*)&qH[id * 8] = hh;
    *(hv8*)&qL[id * 8] = ll;
  } else {
    const size_t e8 = id - NE8;
    const float4 f0 = *(const float4*)&f[e8 * 8];
    const float4 f1 = *(const float4*)&f[e8 * 8 + 4];
    const float fa[8] = {f0.x, f0.y, f0.z, f0.w, f1.x, f1.y, f1.z, f1.w};
    hv8 hh;
#pragma unroll
    for (int e = 0; e < 8; ++e) hh[e] = (_Float16)fa[e];
    *(hv8*)&fH[e8 * 8] = hh;
  }
}

// ---------------------------------------------------------------------------
// Fused 3-GEMM, one dispatch, grid (680, 7):
//  y 0-1 : value = f16(fH @ WvT^T + bv) -> head planes, 128 cols per y
//  y 2-5 : coords = ((qH+qL) @ Woff + boff + ref)*W - 0.5, 64 cols per y
//  y 6   : logits = f16(qH @ WaT^T + ba), 128 cols
// K-loop: all-DMA staging (global_load_lds w16), dbuf chunks, vmcnt(N)+raw
// barriers (never vmcnt(0) until last iter).
// ---------------------------------------------------------------------------
__global__ __launch_bounds__(256) void gemm3(
    const _Float16* __restrict__ fH, const _Float16* __restrict__ qH,
    const _Float16* __restrict__ qL,
    const _Float16* __restrict__ WvT, const _Float16* __restrict__ WoffT2,
    const _Float16* __restrict__ WaT,
    const float* __restrict__ bv, const float* __restrict__ boff,
    const float* __restrict__ ba, const float* __restrict__ refpts,
    _Float16* __restrict__ value16, float* __restrict__ coords,
    _Float16* __restrict__ logits16)
{
  __shared__ _Float16 L[2][8192];   // 32 KB

  const int tid = threadIdx.x, lane = tid & 63, wave = tid >> 6;
  const int l15 = lane & 15, quad = lane >> 4;
  const int r4 = lane >> 2, k4 = (lane & 3) * 8;
  const int rowBase = blockIdx.x * 64;
  const int y = blockIdx.y;

  if (y < 2 || y == 6) {
    // ---- value (y<2) / logits (y==6): A @ Bt, 128 cols ----
    const _Float16* A  = (y == 6) ? qH : fH;
    const _Float16* Bt = (y == 6) ? WaT : WvT;
    const int colBase  = (y == 6) ? 0 : y * 128;

    auto issue = [&](int it) {
      const int buf = it & 1, k0 = it * 32;
      gl_lds16(&A [(size_t)(rowBase + wave * 16 + r4) * 256 + k0 + k4], &L[buf][(wave * 16) * 32]);
      gl_lds16(&Bt[(size_t)(colBase + wave * 32 + r4) * 256 + k0 + k4], &L[buf][2048 + (wave * 32) * 32]);
      gl_lds16(&Bt[(size_t)(colBase + wave * 32 + 16 + r4) * 256 + k0 + k4], &L[buf][2048 + (wave * 32 + 16) * 32]);
    };
    issue(0); issue(1);

    fv4 acc[4][2] = {};
#pragma unroll
    for (int it = 0; it < 8; ++it) {
      const int buf = it & 1;
      if (it == 7) WAIT_VM(0); else WAIT_VM(3);
      BAR();
      hv8 af[4];
#pragma unroll
      for (int i = 0; i < 4; ++i)
        af[i] = *(const hv8*)&L[buf][(i * 16 + l15) * 32 + quad * 8];
#pragma unroll
      for (int j = 0; j < 2; ++j) {
        const hv8 bf = *(const hv8*)&L[buf][2048 + (wave * 32 + j * 16 + l15) * 32 + quad * 8];
#pragma unroll
        for (int i = 0; i < 4; ++i)
          acc[i][j] = __builtin_amdgcn_mfma_f32_16x16x32_f16(af[i], bf, acc[i][j], 0, 0, 0);
      }
      WAIT_LGKM0();
      BAR();
      if (it + 2 < 8) issue(it + 2);
    }

    const float* bias = (y == 6) ? ba : bv;
#pragma unroll
    for (int j = 0; j < 2; ++j) {
      const int col = colBase + wave * 32 + j * 16 + l15;
      const float bj = bias[col];
#pragma unroll
      for (int i = 0; i < 4; ++i)
#pragma unroll
        for (int rg = 0; rg < 4; ++rg) {
          const int row = rowBase + i * 16 + quad * 4 + rg;
          const float v = acc[i][j][rg] + bj;
          if (y == 6) {
            logits16[(size_t)row * 128 + col] = (_Float16)v;
          } else {
            const int n = (row >= LEN_IN) ? 1 : 0;
            const int pix = row - n * LEN_IN;
            const int m = col >> 5, d = col & 31;
            value16[((size_t)(n * 8 + m) * LEN_IN + pix) * 32 + d] = (_Float16)v;
          }
        }
    }
  } else {
    // ---- coords (y 2-5): f16-split A and B, 3 MFMAs, 64 cols ----
    const int c0 = (y - 2) * 64;

    auto issue = [&](int it) {
      const int buf = it & 1, k0 = it * 32;
      gl_lds16(&qH[(size_t)(rowBase + wave * 16 + r4) * 256 + k0 + k4], &L[buf][(wave * 16) * 32]);
      gl_lds16(&qL[(size_t)(rowBase + wave * 16 + r4) * 256 + k0 + k4], &L[buf][2048 + (wave * 16) * 32]);
      gl_lds16(&WoffT2[(size_t)(c0 + wave * 16 + r4) * 256 + k0 + k4], &L[buf][4096 + (wave * 16) * 32]);
      gl_lds16(&WoffT2[(size_t)(256 + c0 + wave * 16 + r4) * 256 + k0 + k4], &L[buf][4096 + (64 + wave * 16) * 32]);
    };
    issue(0); issue(1);

    fv4 acc[4] = {};
#pragma unroll
    for (int it = 0; it < 8; ++it) {
      const int buf = it & 1;
      if (it == 7) WAIT_VM(0); else WAIT_VM(4);
      BAR();
      hv8 ah[4], al[4];
#pragma unroll
      for (int i = 0; i < 4; ++i) {
        ah[i] = *(const hv8*)&L[buf][(i * 16 + l15) * 32 + quad * 8];
        al[i] = *(const hv8*)&L[buf][2048 + (i * 16 + l15) * 32 + quad * 8];
      }
      const hv8 bh = *(const hv8*)&L[buf][4096 + (wave * 16 + l15) * 32 + quad * 8];
      const hv8 bl = *(const hv8*)&L[buf][4096 + (64 + wave * 16 + l15) * 32 + quad * 8];
#pragma unroll
      for (int i = 0; i < 4; ++i) {
        acc[i] = __builtin_amdgcn_mfma_f32_16x16x32_f16(ah[i], bh, acc[i], 0, 0, 0);
        acc[i] = __builtin_amdgcn_mfma_f32_16x16x32_f16(ah[i], bl, acc[i], 0, 0, 0);
        acc[i] = __builtin_amdgcn_mfma_f32_16x16x32_f16(al[i], bh, acc[i], 0, 0, 0);
      }
      WAIT_LGKM0();
      BAR();
      if (it + 2 < 8) issue(it + 2);
    }

    // col c = (((m*4+l)*4+p)*2+xy); write (acc + boff + ref) * W - 0.5
    const int c = c0 + wave * 16 + l15;
    const int xy = c & 1, l = (c >> 3) & 3;
    const float Wl = (float)(128 >> l);
    const float bj = boff[c];
#pragma unroll
    for (int i = 0; i < 4; ++i)
#pragma unroll
      for (int rg = 0; rg < 4; ++rg) {
        const int row = rowBase + i * 16 + quad * 4 + rg;
        const float ref = refpts[(size_t)row * 8 + l * 2 + xy];
        coords[(size_t)row * 256 + c] = (acc[i][rg] + bj + ref) * Wl - 0.5f;
      }
  }
}

// ---------------------------------------------------------------------------
// Final GEMM: out = fp32(outp16 @ WoT^T + bo). Same all-DMA skeleton.
// Grid (680, 2).
// ---------------------------------------------------------------------------
__global__ __launch_bounds__(256) void gemm_out(
    const _Float16* __restrict__ A, const _Float16* __restrict__ Bt,
    const float* __restrict__ bias, float* __restrict__ C)
{
  __shared__ _Float16 L[2][6144];

  const int tid = threadIdx.x, lane = tid & 63, wave = tid >> 6;
  const int l15 = lane & 15, quad = lane >> 4;
  const int r4 = lane >> 2, k4 = (lane & 3) * 8;
  const int rowBase = blockIdx.x * 64;
  const int colBase = blockIdx.y * 128;

  auto issue = [&](int it) {
    const int buf = it & 1, k0 = it * 32;
    gl_lds16(&A [(size_t)(rowBase + wave * 16 + r4) * 256 + k0 + k4], &L[buf][(wave * 16) * 32]);
    gl_lds16(&Bt[(size_t)(colBase + wave * 32 + r4) * 256 + k0 + k4], &L[buf][2048 + (wave * 32) * 32]);
    gl_lds16(&Bt[(size_t)(colBase + wave * 32 + 16 + r4) * 256 + k0 + k4], &L[buf][2048 + (wave * 32 + 16) * 32]);
  };
  issue(0); issue(1);

  fv4 acc[4][2] = {};
#pragma unroll
  for (int it = 0; it < 8; ++it) {
    const int buf = it & 1;
    if (it == 7) WAIT_VM(0); else WAIT_VM(3);
    BAR();
    hv8 af[4];
#pragma unroll
    for (int i = 0; i < 4; ++i)
      af[i] = *(const hv8*)&L[buf][(i * 16 + l15) * 32 + quad * 8];
#pragma unroll
    for (int j = 0; j < 2; ++j) {
      const hv8 bf = *(const hv8*)&L[buf][2048 + (wave * 32 + j * 16 + l15) * 32 + quad * 8];
#pragma unroll
      for (int i = 0; i < 4; ++i)
        acc[i][j] = __builtin_amdgcn_mfma_f32_16x16x32_f16(af[i], bf, acc[i][j], 0, 0, 0);
    }
    WAIT_LGKM0();
    BAR();
    if (it + 2 < 8) issue(it + 2);
  }

#pragma unroll
  for (int j = 0; j < 2; ++j) {
    const int col = colBase + wave * 32 + j * 16 + l15;
    const float bj = bias[col];
#pragma unroll
    for (int i = 0; i < 4; ++i)
#pragma unroll
      for (int rg = 0; rg < 4; ++rg) {
        const int row = rowBase + i * 16 + quad * 4 + rg;
        C[(size_t)row * 256 + col] = acc[i][j][rg] + bj;
      }
  }
}

// ---------------------------------------------------------------------------
// Sampler (unchanged: ~70 us, conflict-free, gather/VALU-bound).
// ---------------------------------------------------------------------------
__global__ __launch_bounds__(256, 6) void sample_kernel(
    const _Float16* __restrict__ value16,  // head planes
    const float* __restrict__ coords,      // (B, LQ, 256) pixel coords
    const _Float16* __restrict__ logits16, // (B, LQ, 128)
    _Float16* __restrict__ outp16)         // (B, LQ, 256)
{
  __shared__ unsigned s_pair[4096];
  __shared__ float    s_attn[1024];

  const int tid = threadIdx.x;
  const int qBase = blockIdx.x * 8;

  if (tid < 64) {
    const hv8* lp = (const hv8*)&logits16[(size_t)(qBase + (tid >> 3)) * 128 + (tid & 7) * 16];
    const hv8 w0 = lp[0], w1 = lp[1];
    float w[16];
#pragma unroll
    for (int e = 0; e < 8; ++e) { w[e] = (float)w0[e]; w[8 + e] = (float)w1[e]; }
    float mx = w[0];
#pragma unroll
    for (int i = 1; i < 16; ++i) mx = fmaxf(mx, w[i]);
    float sum = 0.f;
#pragma unroll
    for (int i = 0; i < 16; ++i) { w[i] = expf(w[i] - mx); sum += w[i]; }
    const float inv = 1.f / sum;
#pragma unroll
    for (int p = 0; p < 16; ++p) s_attn[p * 64 + tid] = w[p] * inv;
  }
  __syncthreads();

#pragma unroll
  for (int k = 0; k < 4; ++k) {
    const int i = tid + 256 * k;
    const int p = i >> 6, q = (i >> 3) & 7, m = i & 7;
    const int l = p >> 2, pp = p & 3;
    const int qg = qBase + q;
    const float2 of = *(const float2*)&coords[(size_t)qg * 256 + ((m * 4 + l) * 4 + pp) * 2];
    const float aw = s_attn[i];
    const int W = 128 >> l;
    const int st = (l == 0) ? 0 : (l == 1) ? 16384 : (l == 2) ? 20480 : 21504;
    const float xf = floorf(of.x), yf = floorf(of.y);
    const int x0 = (int)xf, y0 = (int)yf;
    const float wx = of.x - xf, wy = of.y - yf;
    uint4 rec;
    unsigned* rp = &rec.x;
#pragma unroll
    for (int c = 0; c < 4; ++c) {
      const int dx = c & 1, dy = c >> 1;
      const int xi = x0 + dx, yi = y0 + dy;
      const bool valid = (xi >= 0) & (xi < W) & (yi >= 0) & (yi < W);
      const float w = (dx ? wx : 1.f - wx) * (dy ? wy : 1.f - wy) * aw;
      union { _Float16 h; unsigned short s; } pk;
      pk.h = (_Float16)w;
      const unsigned idx = (unsigned)(st + yi * W + xi);
      rp[c] = valid ? (idx | ((unsigned)pk.s << 16)) : 0u;
    }
    *(uint4*)&s_pair[i * 4] = rec;
  }
  __syncthreads();

  const int wave = tid >> 6, lane = tid & 63;
  const int qloc = wave * 2 + (lane >> 5);
  const int sub = lane & 31, m = sub >> 2, j = sub & 3;
  const int qg = qBase + qloc;
  const int n = (qg >= LEN_IN) ? 1 : 0;
  const char* base = (const char*)value16 + (size_t)(n * 8 + m) * LEN_IN * 64 + j * 16;
  const int lb = qloc * 8 + m;

  float acc8[8] = {0.f, 0.f, 0.f, 0.f, 0.f, 0.f, 0.f, 0.f};
#pragma unroll 4
  for (int p = 0; p < 16; ++p) {
    const uint4 u4 = *(const uint4*)&s_pair[(p * 64 + lb) * 4];
    const unsigned uu[4] = {u4.x, u4.y, u4.z, u4.w};
#pragma unroll
    for (int c = 0; c < 4; ++c) {
      const unsigned u = uu[c];
      union { unsigned short s; _Float16 h; } pk;
      pk.s = (unsigned short)(u >> 16);
      const float w = (float)pk.h;
      const hv8 v = *(const hv8*)(base + (size_t)(u & 32767u) * 64);
#pragma unroll
      for (int e = 0; e < 8; ++e) acc8[e] = fmaf(w, (float)v[e], acc8[e]);
    }
  }

  hv8 o;
#pragma unroll
  for (int e = 0; e < 8; ++e) o[e] = (_Float16)acc8[e];
  *(hv8*)&outp16[(size_t)qg * 256 + m * 32 + j * 8] = o;
}

// ---------------------------------------------------------------------------
extern "C" void kernel_launch(void* const* d_in, const int* in_sizes, int n_in,
                              void* d_out, int out_size, void* d_ws, size_t ws_size,
                              hipStream_t stream) {
  const float* query   = (const float*)d_in[0];
  const float* refpts  = (const float*)d_in[1];
  const float* flatten = (const float*)d_in[2];
  const float* Wv   = (const float*)d_in[5];
  const float* bv   = (const float*)d_in[6];
  const float* Woff = (const float*)d_in[7];
  const float* boff = (const float*)d_in[8];
  const float* Wa   = (const float*)d_in[9];
  const float* ba   = (const float*)d_in[10];
  const float* Wo   = (const float*)d_in[11];
  const float* bo   = (const float*)d_in[12];
  float* out = (float*)d_out;

  // Workspace (~145 MB): value16 | coords | logits16 | qH | qL | fH | weights
  // outp16 aliases fH (fH dead after gemm3; sampler runs after).
  const size_t NE = (size_t)MROWS * 256;            // 11,141,120
  _Float16* value16  = (_Float16*)d_ws;             // NE
  float*    coords   = (float*)(value16 + NE);      // NE fp32
  _Float16* logits16 = (_Float16*)(coords + NE);    // NE/2
  _Float16* qH       = logits16 + NE / 2;           // NE
  _Float16* qL       = qH + NE;                     // NE
  _Float16* fH       = qL + NE;                     // NE
  _Float16* outp16   = fH;                          // alias
  _Float16* WvT      = fH + NE;                     // 256*256
  _Float16* WoffT2   = WvT + 256 * 256;             // 512*256
  _Float16* WaT      = WoffT2 + 512 * 256;          // 128*256
  _Float16* WoT      = WaT + 128 * 256;             // 256*256

  const dim3 blk(256);

  cvt_weights<<<dim3(56), blk, 0, stream>>>(Wv, Woff, Wa, Wo, WvT, WoffT2, WaT, WoT);
  cvt_acts<<<dim3(10880), blk, 0, stream>>>(query, flatten, qH, qL, fH);

  // value + coords + logits in ONE dispatch
  gemm3<<<dim3(MROWS / 64, 7), blk, 0, stream>>>(fH, qH, qL, WvT, WoffT2, WaT,
      bv, boff, ba, refpts, value16, coords, logits16);

  // sampling -> outp16 (f16, aliases fH)
  sample_kernel<<<dim3(MROWS / 8), blk, 0, stream>>>(value16, coords, logits16, outp16);

  // out = outp16 @ Wo + bo
  gemm_out<<<dim3(MROWS / 64, 2), blk, 0, stream>>>(outp16, WoT, bo, out);
}